// Round 11
// baseline (288.663 us; speedup 1.0000x reference)
//
#include <hip/hip_runtime.h>
#include <stdint.h>

#define NN    100000
#define FIN   128
#define HIDN  64
#define NCLS  40
#define NE    1600000
#define NBUCK ((NN + 255) / 256)      // 391 buckets of 256 nodes
#define EPB   4096                    // edges per partition block
#define NEB   ((NE + EPB - 1) / EPB)  // 391 partition blocks

typedef unsigned int uint32;
typedef short bf16x8 __attribute__((ext_vector_type(8)));
typedef float f32x4 __attribute__((ext_vector_type(4)));

static __device__ __forceinline__ unsigned short f2bf(float f) {
  uint32 u = __float_as_uint(f);
  u = (u + 0x7fffu + ((u >> 16) & 1u)) >> 16;   // RNE
  return (unsigned short)u;
}
static __device__ __forceinline__ uint32 pack2(float lo, float hi) {
  return (uint32)f2bf(lo) | ((uint32)f2bf(hi) << 16);
}
static __device__ __forceinline__ float bf_lo(uint32 v) {
  return __uint_as_float(v << 16);
}
static __device__ __forceinline__ float bf_hi(uint32 v) {
  return __uint_as_float(v & 0xFFFF0000u);
}

// ---- edge dtype probe: int64 (odd u32 words all zero) vs int32 ----
__global__ __launch_bounds__(64) void probe_kernel(const unsigned int* __restrict__ raw,
                                                   int* __restrict__ flag) {
  if (threadIdx.x == 0) {
    int is64 = 1;
    for (int i = 0; i < 64; ++i)
      if (raw[2 * i + 1] != 0u) { is64 = 0; break; }
    *flag = is64;
  }
}

// ---- passA: per-block bucket histogram -> mat[blk][bucket] ----
__global__ __launch_bounds__(256) void passA_kernel(const void* __restrict__ eptr,
                                                    const int* __restrict__ flag,
                                                    int* __restrict__ mat) {
  __shared__ int cnt[NBUCK];
  int tid = threadIdx.x;
  for (int i = tid; i < NBUCK; i += 256) cnt[i] = 0;
  __syncthreads();
  int is64 = *flag;
  int base = blockIdx.x * EPB;
#pragma unroll
  for (int k = 0; k < EPB / 256; ++k) {
    int e = base + k * 256 + tid;
    if (e < NE) {
      int d = is64 ? (int)((const long long*)eptr)[e + NE]
                   : ((const int*)eptr)[e + NE];
      atomicAdd(&cnt[d >> 8], 1);
    }
  }
  __syncthreads();
  for (int i = tid; i < NBUCK; i += 256)
    mat[blockIdx.x * NBUCK + i] = cnt[i];
}

// ---- passB1: per-bucket exclusive scan over blocks; emit bucket totals ----
__global__ __launch_bounds__(512) void passB1_kernel(int* __restrict__ mat,
                                                     int* __restrict__ tot) {
  __shared__ int s[512];
  int b = blockIdx.x;         // bucket
  int t = threadIdx.x;        // block index
  int v = (t < NEB) ? mat[t * NBUCK + b] : 0;
  s[t] = v;
  __syncthreads();
#pragma unroll
  for (int d = 1; d < 512; d <<= 1) {
    int u = (t >= d) ? s[t - d] : 0;
    __syncthreads();
    s[t] += u;
    __syncthreads();
  }
  if (t < NEB) mat[t * NBUCK + b] = s[t] - v;  // exclusive prefix within bucket
  if (t == 511) tot[b] = s[511];
}

// ---- passB2: exclusive scan of bucket totals -> bbase ----
__global__ __launch_bounds__(512) void passB2_kernel(const int* __restrict__ tot,
                                                     int* __restrict__ bbase) {
  __shared__ int s[512];
  int i = threadIdx.x;
  int v = (i < NBUCK) ? tot[i] : 0;
  s[i] = v;
  __syncthreads();
#pragma unroll
  for (int d = 1; d < 512; d <<= 1) {
    int u = (i >= d) ? s[i - d] : 0;
    __syncthreads();
    s[i] += u;
    __syncthreads();
  }
  if (i < NBUCK) bbase[i] = s[i] - v;
  if (i == 511) bbase[NBUCK] = s[511];
}

// ---- passC: place edges into compact bucket-sorted bbuf (LDS cursors) ----
__global__ __launch_bounds__(256) void passC_kernel(const void* __restrict__ eptr,
                                                    const int* __restrict__ flag,
                                                    const int* __restrict__ mat,
                                                    const int* __restrict__ bbase,
                                                    uint32* __restrict__ bbuf) {
  __shared__ int cur[NBUCK];
  int tid = threadIdx.x;
  for (int i = tid; i < NBUCK; i += 256)
    cur[i] = bbase[i] + mat[blockIdx.x * NBUCK + i];
  __syncthreads();
  int is64 = *flag;
  int base = blockIdx.x * EPB;
#pragma unroll
  for (int k = 0; k < EPB / 256; ++k) {
    int e = base + k * 256 + tid;
    if (e < NE) {
      int s, d;
      if (is64) {
        const long long* p = (const long long*)eptr;
        s = (int)p[e]; d = (int)p[e + NE];
      } else {
        const int* p = (const int*)eptr;
        s = p[e]; d = p[e + NE];
      }
      int slot = atomicAdd(&cur[d >> 8], 1);
      bbuf[slot] = (uint32)s | ((uint32)(d & 255) << 17);
    }
  }
}

// ---- build: per-bucket CSR (LDS hist + scan + rank placement) ----
__global__ __launch_bounds__(256) void build_kernel(const int* __restrict__ bbase,
                                                    const uint32* __restrict__ bbuf,
                                                    int* __restrict__ off,
                                                    float* __restrict__ dinv,
                                                    int* __restrict__ s_src) {
  __shared__ int hist[256];
  __shared__ int lofs[256];
  __shared__ int rank[256];
  int b = blockIdx.x, tid = threadIdx.x;
  int base = bbase[b];
  int count = bbase[b + 1] - base;
  const uint32* p = bbuf + base;
  hist[tid] = 0;
  __syncthreads();
  for (int i = tid; i < count; i += 256) atomicAdd(&hist[p[i] >> 17], 1);
  __syncthreads();
  int deg = hist[tid];
  lofs[tid] = deg;
  __syncthreads();
#pragma unroll
  for (int dd = 1; dd < 256; dd <<= 1) {
    int t = (tid >= dd) ? lofs[tid - dd] : 0;
    __syncthreads();
    lofs[tid] += t;
    __syncthreads();
  }
  int excl = lofs[tid] - deg;
  __syncthreads();
  lofs[tid] = excl;
  rank[tid] = 0;
  int n = b * 256 + tid;
  if (n < NN) {
    off[n] = base + excl;
    dinv[n] = rsqrtf((float)deg + 1.0f);
  }
  if (b == 0 && tid == 0) off[NN] = NE;
  __syncthreads();
  for (int i = tid; i < count; i += 256) {
    uint32 v = p[i];
    int dl = (int)(v >> 17);
    int s = (int)(v & 0x1FFFFu);
    int r = atomicAdd(&rank[dl], 1);
    s_src[base + lofs[dl] + r] = s;
  }
}

// ---- GEMM1 (MFMA): hs[N,64](bf16) = (x@W1)*dinv. 64 rows/block, 4 waves,
// each wave one 16x64 tile: 4 n-tiles x 4 K-steps of mfma_f32_16x16x32_bf16.
// W1 pre-packed to LDS B-frags; epilogue staged via padded LDS for coalesced
// 128 B/row stores (avoids scattered C-layout stores). ----
__global__ __launch_bounds__(256) void gemm1_kernel(const float* __restrict__ x,
                                                    const float* __restrict__ W,
                                                    const float* __restrict__ dinv,
                                                    uint32* __restrict__ hs) {
  __shared__ uint32 sB[4 * 4 * 64 * 4];   // [tile][kstep][lane][4 dw] 16 KB
  __shared__ uint32 sC[4][16][33];        // per-wave C staging, +1 pad, 8.4 KB
  int tid = threadIdx.x;
  // build B fragments: elem j of lane = W[kstep*32 + (lane>>4)*8 + j][tile*16 + (lane&15)]
  for (int e = tid; e < 1024; e += 256) {
    int tile = e >> 8, kstep = (e >> 6) & 3, lane = e & 63;
    int n = tile * 16 + (lane & 15);
    int kb = kstep * 32 + (lane >> 4) * 8;
    uint32* dst = &sB[(((tile * 4 + kstep) * 64) + lane) * 4];
#pragma unroll
    for (int j = 0; j < 4; ++j) {
      float lo = W[(kb + 2 * j) * HIDN + n];
      float hi = W[(kb + 2 * j + 1) * HIDN + n];
      dst[j] = pack2(lo, hi);
    }
  }
  __syncthreads();
  int wid = tid >> 6, lane = tid & 63;
  int rbase = blockIdx.x * 64 + wid * 16;
  int m = lane & 15, kq = lane >> 4;
  bool vA = (rbase + m) < NN;
  const float* xrow = x + (size_t)(rbase + m) * FIN + kq * 8;
  f32x4 acc[4];
#pragma unroll
  for (int t = 0; t < 4; ++t) acc[t] = (f32x4){0.f, 0.f, 0.f, 0.f};
#pragma unroll
  for (int kstep = 0; kstep < 4; ++kstep) {
    float4 xa = make_float4(0.f, 0.f, 0.f, 0.f);
    float4 xb = make_float4(0.f, 0.f, 0.f, 0.f);
    if (vA) {
      xa = *(const float4*)(xrow + kstep * 32);
      xb = *(const float4*)(xrow + kstep * 32 + 4);
    }
    union { uint32 u[4]; bf16x8 v; } ua;
    ua.u[0] = pack2(xa.x, xa.y); ua.u[1] = pack2(xa.z, xa.w);
    ua.u[2] = pack2(xb.x, xb.y); ua.u[3] = pack2(xb.z, xb.w);
#pragma unroll
    for (int tile = 0; tile < 4; ++tile) {
      bf16x8 b = *(const bf16x8*)&sB[(((tile * 4 + kstep) * 64) + lane) * 4];
      acc[tile] = __builtin_amdgcn_mfma_f32_16x16x32_bf16(ua.v, b, acc[tile], 0, 0, 0);
    }
  }
  // epilogue: C layout col=lane&15, row=(lane>>4)*4+reg; scale, pack, stage
  float dv[4];
#pragma unroll
  for (int reg = 0; reg < 4; ++reg) {
    int rr = rbase + kq * 4 + reg;
    dv[reg] = (rr < NN) ? dinv[rr] : 0.f;
  }
  unsigned short* sCh = (unsigned short*)&sC[wid][0][0];
#pragma unroll
  for (int tile = 0; tile < 4; ++tile) {
#pragma unroll
    for (int reg = 0; reg < 4; ++reg) {
      int row = kq * 4 + reg;
      int col = tile * 16 + (lane & 15);
      sCh[row * 66 + col] = f2bf(acc[tile][reg] * dv[reg]);
    }
  }
  __builtin_amdgcn_s_waitcnt(0);  // lgkmcnt(0): own-wave LDS writes visible
  int r = lane >> 2, c4 = lane & 3;
  int rr = rbase + r;
  if (rr < NN) {
    const uint4* sp = (const uint4*)&sC[wid][r][c4 * 8];
    uint4* hp = (uint4*)&hs[(size_t)rr * 32 + c4 * 8];
    hp[0] = sp[0];
    hp[1] = sp[1];
  }
}

// ---- agg1: 8 lanes/edge (uint4=16B), 8 edge slots/wave, unroll x2 ->
// 16 gathers in flight. g[n] = bf16(dinv_n*relu(dinv_n*(hs[n]+sum)+b1)) ----
__global__ __launch_bounds__(256) void agg1_kernel(const int* __restrict__ off,
                                                   const int* __restrict__ s_src,
                                                   const uint4* __restrict__ hs4,
                                                   const float* __restrict__ dinv,
                                                   const float* __restrict__ b1,
                                                   uint4* __restrict__ g) {
  int n = blockIdx.x * 4 + (threadIdx.x >> 6);     // NN = 25000*4 exactly
  int lane = threadIdx.x & 63;
  int q = lane >> 3;           // edge slot 0..7
  int hc = lane & 7;           // 8-col chunk (cols 8hc..8hc+7)
  int j0 = off[n], j1 = off[n + 1];
  float a[8];
#pragma unroll
  for (int i = 0; i < 8; ++i) a[i] = 0.f;
  if (q == 0) {
    uint4 v = hs4[(size_t)n * 8 + hc];
    a[0] = bf_lo(v.x); a[1] = bf_hi(v.x); a[2] = bf_lo(v.y); a[3] = bf_hi(v.y);
    a[4] = bf_lo(v.z); a[5] = bf_hi(v.z); a[6] = bf_lo(v.w); a[7] = bf_hi(v.w);
  }
  int j = j0 + q;
  for (; j + 8 < j1; j += 16) {
    int sa = s_src[j], sb = s_src[j + 8];
    uint4 va = hs4[(size_t)sa * 8 + hc];
    uint4 vb = hs4[(size_t)sb * 8 + hc];
    a[0] += bf_lo(va.x); a[1] += bf_hi(va.x); a[2] += bf_lo(va.y); a[3] += bf_hi(va.y);
    a[4] += bf_lo(va.z); a[5] += bf_hi(va.z); a[6] += bf_lo(va.w); a[7] += bf_hi(va.w);
    a[0] += bf_lo(vb.x); a[1] += bf_hi(vb.x); a[2] += bf_lo(vb.y); a[3] += bf_hi(vb.y);
    a[4] += bf_lo(vb.z); a[5] += bf_hi(vb.z); a[6] += bf_lo(vb.w); a[7] += bf_hi(vb.w);
  }
  if (j < j1) {
    int sa = s_src[j];
    uint4 va = hs4[(size_t)sa * 8 + hc];
    a[0] += bf_lo(va.x); a[1] += bf_hi(va.x); a[2] += bf_lo(va.y); a[3] += bf_hi(va.y);
    a[4] += bf_lo(va.z); a[5] += bf_hi(va.z); a[6] += bf_lo(va.w); a[7] += bf_hi(va.w);
  }
#pragma unroll
  for (int i = 0; i < 8; ++i) {
    a[i] += __shfl_xor(a[i], 8, 64);
    a[i] += __shfl_xor(a[i], 16, 64);
    a[i] += __shfl_xor(a[i], 32, 64);
  }
  if (q == 0) {
    float di = dinv[n];
    float4 b0 = *(const float4*)&b1[hc * 8];
    float4 b4 = *(const float4*)&b1[hc * 8 + 4];
    float r0 = di * fmaxf(a[0] * di + b0.x, 0.f);
    float r1 = di * fmaxf(a[1] * di + b0.y, 0.f);
    float r2 = di * fmaxf(a[2] * di + b0.z, 0.f);
    float r3 = di * fmaxf(a[3] * di + b0.w, 0.f);
    float r4 = di * fmaxf(a[4] * di + b4.x, 0.f);
    float r5 = di * fmaxf(a[5] * di + b4.y, 0.f);
    float r6 = di * fmaxf(a[6] * di + b4.z, 0.f);
    float r7 = di * fmaxf(a[7] * di + b4.w, 0.f);
    uint4 o;
    o.x = pack2(r0, r1); o.y = pack2(r2, r3);
    o.z = pack2(r4, r5); o.w = pack2(r6, r7);
    g[(size_t)n * 8 + hc] = o;    // 8 lanes x 16 B = 128 B contiguous
  }
}

// ---- agg2 fused with W2 matvec: out[n] = dinv_n*(g[n]+sum g[s_j]) @ W2 + b2.
// After the q-reduction every lane holds its 8-col chunk of t; the 64x40
// matvec runs in-wave vs LDS W2 (stride 41 -> <=2-way banks) + hc-shfl. ----
__global__ __launch_bounds__(256) void agg2_kernel(const int* __restrict__ off,
                                                   const int* __restrict__ s_src,
                                                   const uint4* __restrict__ g,
                                                   const float* __restrict__ dinv,
                                                   const float* __restrict__ W2,
                                                   const float* __restrict__ b2,
                                                   float* __restrict__ out) {
  __shared__ float sW2[HIDN * 41];   // 10.5 KB, padded stride
  int tid = threadIdx.x;
  for (int i = tid; i < HIDN * NCLS; i += 256) {
    int k = i / NCLS, c = i - k * NCLS;
    sW2[k * 41 + c] = W2[i];
  }
  __syncthreads();
  int n = blockIdx.x * 4 + (tid >> 6);
  int lane = tid & 63;
  int q = lane >> 3;
  int hc = lane & 7;
  int j0 = off[n], j1 = off[n + 1];
  float a[8];
#pragma unroll
  for (int i = 0; i < 8; ++i) a[i] = 0.f;
  if (q == 0) {
    uint4 v = g[(size_t)n * 8 + hc];
    a[0] = bf_lo(v.x); a[1] = bf_hi(v.x); a[2] = bf_lo(v.y); a[3] = bf_hi(v.y);
    a[4] = bf_lo(v.z); a[5] = bf_hi(v.z); a[6] = bf_lo(v.w); a[7] = bf_hi(v.w);
  }
  int j = j0 + q;
  for (; j + 8 < j1; j += 16) {
    int sa = s_src[j], sb = s_src[j + 8];
    uint4 va = g[(size_t)sa * 8 + hc];
    uint4 vb = g[(size_t)sb * 8 + hc];
    a[0] += bf_lo(va.x); a[1] += bf_hi(va.x); a[2] += bf_lo(va.y); a[3] += bf_hi(va.y);
    a[4] += bf_lo(va.z); a[5] += bf_hi(va.z); a[6] += bf_lo(va.w); a[7] += bf_hi(va.w);
    a[0] += bf_lo(vb.x); a[1] += bf_hi(vb.x); a[2] += bf_lo(vb.y); a[3] += bf_hi(vb.y);
    a[4] += bf_lo(vb.z); a[5] += bf_hi(vb.z); a[6] += bf_lo(vb.w); a[7] += bf_hi(vb.w);
  }
  if (j < j1) {
    int sa = s_src[j];
    uint4 va = g[(size_t)sa * 8 + hc];
    a[0] += bf_lo(va.x); a[1] += bf_hi(va.x); a[2] += bf_lo(va.y); a[3] += bf_hi(va.y);
    a[4] += bf_lo(va.z); a[5] += bf_hi(va.z); a[6] += bf_lo(va.w); a[7] += bf_hi(va.w);
  }
#pragma unroll
  for (int i = 0; i < 8; ++i) {
    a[i] += __shfl_xor(a[i], 8, 64);
    a[i] += __shfl_xor(a[i], 16, 64);
    a[i] += __shfl_xor(a[i], 32, 64);
  }
  // in-wave matvec: lane (q,hc) computes cols q*5..q*5+4 over k in hc chunk
  float partial[5];
#pragma unroll
  for (int jj = 0; jj < 5; ++jj) partial[jj] = 0.f;
#pragma unroll
  for (int i = 0; i < 8; ++i) {
    const float* wr = &sW2[(hc * 8 + i) * 41 + q * 5];
#pragma unroll
    for (int jj = 0; jj < 5; ++jj)
      partial[jj] = fmaf(a[i], wr[jj], partial[jj]);
  }
#pragma unroll
  for (int jj = 0; jj < 5; ++jj) {
    partial[jj] += __shfl_xor(partial[jj], 1, 64);
    partial[jj] += __shfl_xor(partial[jj], 2, 64);
    partial[jj] += __shfl_xor(partial[jj], 4, 64);
  }
  if (hc == 0) {
    float di = dinv[n];
    int c0 = q * 5;
#pragma unroll
    for (int jj = 0; jj < 5; ++jj)
      out[(size_t)n * NCLS + c0 + jj] = di * partial[jj] + b2[c0 + jj];
  }
}

extern "C" void kernel_launch(void* const* d_in, const int* in_sizes, int n_in,
                              void* d_out, int out_size, void* d_ws, size_t ws_size,
                              hipStream_t stream) {
  const float* x  = (const float*)d_in[0];
  const void*  ei = d_in[1];
  const float* W1 = (const float*)d_in[2];
  const float* b1 = (const float*)d_in[3];
  const float* W2 = (const float*)d_in[4];
  const float* b2 = (const float*)d_in[5];
  float* out = (float*)d_out;

  char* w = (char*)d_ws;
  size_t off_b = 0;
  auto carve = [&](size_t bytes) -> void* {
    void* p = w + off_b;
    off_b = (off_b + bytes + 255) & ~(size_t)255;
    return p;
  };
  int*    mat   = (int*)   carve((size_t)NEB * NBUCK * 4);   // 611 KB
  int*    tot   = (int*)   carve((size_t)NBUCK * 4);
  int*    bbase = (int*)   carve((size_t)(NBUCK + 1) * 4);
  int*    offs  = (int*)   carve((size_t)(NN + 1) * 4);
  float*  dinv  = (float*) carve((size_t)NN * 4);
  int*    flag  = (int*)   carve(256);
  int*    s_src = (int*)   carve((size_t)NE * 4);
  uint32* hs    = (uint32*)carve((size_t)NN * 32 * 4);       // bf16 h, 12.8 MB
  uint4*  g     = (uint4*) carve((size_t)NN * 8 * 16);       // bf16 g, 12.8 MB
  uint32* bbuf  = (uint32*)carve((size_t)NE * 4);            // 6.4 MB

  probe_kernel<<<1, 64, 0, stream>>>((const unsigned int*)ei, flag);
  passA_kernel<<<NEB, 256, 0, stream>>>(ei, flag, mat);
  passB1_kernel<<<NBUCK, 512, 0, stream>>>(mat, tot);
  passB2_kernel<<<1, 512, 0, stream>>>(tot, bbase);
  passC_kernel<<<NEB, 256, 0, stream>>>(ei, flag, mat, bbase, bbuf);
  build_kernel<<<NBUCK, 256, 0, stream>>>(bbase, bbuf, offs, dinv, s_src);
  gemm1_kernel<<<(NN + 63) / 64, 256, 0, stream>>>(x, W1, dinv, hs);
  agg1_kernel<<<NN / 4, 256, 0, stream>>>(offs, s_src, (const uint4*)hs, dinv, b1, g);
  agg2_kernel<<<NN / 4, 256, 0, stream>>>(offs, s_src, g, dinv, W2, b2, out);
}